// Round 8
// baseline (1312.286 us; speedup 1.0000x reference)
//
#include <hip/hip_runtime.h>
#include <cmath>

// PropConv: K=10 hop gated propagation on a fixed graph + output MLP.
// R8: XCD-pinned column panels. State panel-major [4][N][32 cols] bf16;
// panel = blockIdx.x & 3, and with round-robin block->XCD dispatch each
// panel (3.2MB < 4MiB) stays resident in 2 XCDs' L2 for the whole kernel
// -> gathers served at L2 BW instead of the ~7TB/s L3 ceiling (R5).
// Unlike R4: 4 panels (not 8), lean 8-lane-segment inner loop, no LDS
// round-trips. Scatter made cursor-atomic-free: deg's incnt atomic returns
// the edge's rank within its dst segment.

#define NNODES 50000
#define NEDGES 1600000
#define DD 128
#define KHOPS 10
#define ALPHA 0.1f
#define NPAN 4
#define PCOLS 32                 // cols per panel; row slice = 8 uint2

typedef short short8 __attribute__((ext_vector_type(8)));
typedef float f32x4 __attribute__((ext_vector_type(4)));

static __device__ __forceinline__ unsigned bf16rne(float x) {
    unsigned u = __float_as_uint(x);
    return (u + 0x7FFFu + ((u >> 16) & 1u)) >> 16;
}
static __device__ __forceinline__ float bf_lo(unsigned w) { return __uint_as_float(w << 16); }
static __device__ __forceinline__ float bf_hi(unsigned w) { return __uint_as_float(w & 0xFFFF0000u); }

// 8-entry gate table: gate MLP has only 8 distinct inputs (etypes).
__global__ void gate_kernel(const float* __restrict__ emb, const float* __restrict__ We1,
                            const float* __restrict__ be1, const float* __restrict__ We2,
                            const float* __restrict__ be2, float* __restrict__ gate) {
    int t = threadIdx.x;
    if (t >= 8) return;
    float acc2 = 0.0f;
    for (int j = 0; j < 32; j++) {
        float a = be1[j];
        for (int k = 0; k < DD; k++) a += emb[t * DD + k] * We1[k * 32 + j];
        float g = 0.5f * a * (1.0f + erff(a * 0.70710678118654752f));  // exact GELU
        acc2 += g * We2[j];
    }
    acc2 += be2[0];
    gate[t] = 1.0f + 1.0f / (1.0f + expf(-acc2));   // 1 + sigmoid
}

// In-degree histogram; the returned old count is the edge's rank within its
// dst segment (any permutation is valid -> cursor atomic eliminated later).
__global__ void deg_in_kernel(const int* __restrict__ dst, int* __restrict__ incnt,
                              int* __restrict__ rank, int E) {
    int e = blockIdx.x * blockDim.x + threadIdx.x;
    if (e < E) rank[e] = atomicAdd(&incnt[dst[e]], 1);
}

// ---- 3-kernel multi-block exclusive scan of incnt -> row_ptr ----
__global__ __launch_bounds__(256) void scan1_kernel(const int* __restrict__ cnt,
                                                    int* __restrict__ excl,
                                                    int* __restrict__ bsum, int N) {
    __shared__ int sh[256];
    int t = threadIdx.x;
    int g = blockIdx.x * 256 + t;
    int v = (g < N) ? cnt[g] : 0;
    sh[t] = v;
    __syncthreads();
    for (int off = 1; off < 256; off <<= 1) {
        int u = 0;
        if (t >= off) u = sh[t - off];
        __syncthreads();
        sh[t] += u;
        __syncthreads();
    }
    if (g < N) excl[g] = sh[t] - v;
    if (t == 255) bsum[blockIdx.x] = sh[255];
}
__global__ __launch_bounds__(256) void scan2_kernel(int* __restrict__ bsum, int nb) {
    __shared__ int sh[256];
    int t = threadIdx.x;
    int v = (t < nb) ? bsum[t] : 0;
    sh[t] = v;
    __syncthreads();
    for (int off = 1; off < 256; off <<= 1) {
        int u = 0;
        if (t >= off) u = sh[t - off];
        __syncthreads();
        sh[t] += u;
        __syncthreads();
    }
    if (t < nb) bsum[t] = sh[t] - v;
}
__global__ __launch_bounds__(256) void scan3_kernel(const int* __restrict__ excl,
                                                    const int* __restrict__ bsum,
                                                    int* __restrict__ row_ptr, int N, int E) {
    int g = blockIdx.x * 256 + threadIdx.x;
    if (g < N) row_ptr[g] = excl[g] + bsum[g >> 8];
    if (g == N) row_ptr[N] = E;
}

// Place edges: pos = row_ptr[dst] + rank (no cursor atomic). Builds outcnt.
__global__ void scatter_kernel(const int* __restrict__ src, const int* __restrict__ dst,
                               const int* __restrict__ ef, const int* __restrict__ rank,
                               const int* __restrict__ row_ptr, int* __restrict__ outcnt,
                               int* __restrict__ epay, int E) {
    int e = blockIdx.x * blockDim.x + threadIdx.x;
    if (e >= E) return;
    int s = src[e];
    int pos = row_ptr[dst[e]] + rank[e];
    epay[pos] = s | (ef[e] << 16);
    atomicAdd(&outcnt[s], 1);
}

// Panel-major bf16: g0[p][n][sub] = bf16(feat*srcn), f0p[p][n][sub] = bf16(feat).
__global__ void pscale_kernel(const float* __restrict__ feat, const int* __restrict__ outcnt,
                              uint2* __restrict__ g0, uint2* __restrict__ f0p, int N) {
    int i = blockIdx.x * blockDim.x + threadIdx.x;   // uint2 units, panel-major
    if (i >= N * 32) return;
    int pan = i / (N * 8);
    int rem = i - pan * (N * 8);
    int node = rem >> 3;
    int sub = rem & 7;
    int oc = outcnt[node]; if (oc < 1) oc = 1;
    float sn = rsqrtf((float)oc);
    float4 v = ((const float4*)feat)[node * 32 + pan * 8 + sub];
    uint2 f, g;
    f.x = bf16rne(v.x) | (bf16rne(v.y) << 16);
    f.y = bf16rne(v.z) | (bf16rne(v.w) << 16);
    g.x = bf16rne(v.x * sn) | (bf16rne(v.y * sn) << 16);
    g.y = bf16rne(v.z * sn) | (bf16rne(v.w * sn) << 16);
    f0p[i] = f;
    g0[i] = g;
}

// Wave = 1 dst node x 1 panel. 8 segments x 8 lanes: segment s handles edges
// j = s, s+8, ...; lane holds uint2 = 4 bf16 cols; one edge gather = 64B from
// the XCD-L2-resident panel. Payload chunk (<=64) loaded coalesced, broadcast
// via shfl. 3-step xor reduction folds the 8 segments; lanes 0-7 write.
__global__ __launch_bounds__(256) void hop_kernel(const uint2* __restrict__ g_in,
                                                  const uint2* __restrict__ f0p,
                                                  const int* __restrict__ incnt,
                                                  const int* __restrict__ outcnt,
                                                  const float* __restrict__ gate_g,
                                                  const int* __restrict__ row_ptr,
                                                  const int* __restrict__ epay,
                                                  uint2* __restrict__ g_out,
                                                  int N, int last) {
    __shared__ float gateL[8];
    if (threadIdx.x < 8) gateL[threadIdx.x] = gate_g[threadIdx.x];
    __syncthreads();
    int pan = blockIdx.x & 3;                    // XCD-pinned (blk%8 -> XCD)
    int node = (blockIdx.x >> 2) * 4 + (threadIdx.x >> 6);
    if (node >= N) return;
    int lane = threadIdx.x & 63;
    int seg = lane >> 3, sub = lane & 7;
    const uint2* gp = g_in + (size_t)pan * N * 8;
    int beg = row_ptr[node], end = row_ptr[node + 1];
    float a0 = 0.f, a1 = 0.f, a2 = 0.f, a3 = 0.f;
    for (int base = beg; base < end; base += 64) {
        int n = end - base; if (n > 64) n = 64;
        int p = 0;
        if (lane < n) p = epay[base + lane];
        int iters = (n + 7) >> 3;                // wave-uniform
        int j = seg;
        for (int t = 0; t < iters; t++, j += 8) {
            bool valid = j < n;
            int pe = __shfl(p, valid ? j : 0, 64);
            if (valid) {
                float c = gateL[(unsigned)pe >> 16];
                uint2 g = gp[(size_t)(pe & 0xFFFF) * 8 + sub];
                a0 += c * bf_lo(g.x); a1 += c * bf_hi(g.x);
                a2 += c * bf_lo(g.y); a3 += c * bf_hi(g.y);
            }
        }
    }
#pragma unroll
    for (int d = 8; d < 64; d <<= 1) {
        a0 += __shfl_xor(a0, d, 64);
        a1 += __shfl_xor(a1, d, 64);
        a2 += __shfl_xor(a2, d, 64);
        a3 += __shfl_xor(a3, d, 64);
    }
    if (lane < 8) {                              // sub = lane
        int ic = incnt[node]; if (ic < 1) ic = 1;
        float dn = rsqrtf((float)ic) * (1.0f - ALPHA);
        uint2 fv = f0p[(size_t)pan * N * 8 + (size_t)node * 8 + lane];
        float h0 = dn * a0 + ALPHA * bf_lo(fv.x);
        float h1 = dn * a1 + ALPHA * bf_hi(fv.x);
        float h2 = dn * a2 + ALPHA * bf_lo(fv.y);
        float h3 = dn * a3 + ALPHA * bf_hi(fv.y);
        float sc = 1.0f;
        if (!last) { int oc = outcnt[node]; if (oc < 1) oc = 1; sc = rsqrtf((float)oc); }
        uint2 o;
        o.x = bf16rne(h0 * sc) | (bf16rne(h1 * sc) << 16);
        o.y = bf16rne(h2 * sc) | (bf16rne(h3 * sc) << 16);
        size_t oidx = last ? ((size_t)node * 32 + pan * 8 + lane)            // row-major for MLP
                           : ((size_t)pan * N * 8 + (size_t)node * 8 + lane); // panel-major
        g_out[oidx] = o;
    }
}

// bf16 MFMA MLP layer (verified gfx950 16x16x32 layouts).
#define ASTR 136
__global__ __launch_bounds__(256) void mlp_mfma_kernel(const unsigned short* __restrict__ in,
                                                       const float* __restrict__ W,
                                                       const float* __restrict__ bias,
                                                       void* __restrict__ outp,
                                                       int N, int mode) {  // mode0: gelu+bf16; mode1: f32
    __shared__ unsigned short As[64 * ASTR];
    __shared__ unsigned short Bs[128 * ASTR];
    int tid = threadIdx.x;
    int row0 = blockIdx.x * 64;
    for (int i = tid; i < 64 * 16; i += 256) {
        int r = i >> 4, c8 = i & 15;
        int gr = row0 + r; if (gr >= N) gr = N - 1;
        uint4 v = *(const uint4*)(in + (size_t)gr * DD + c8 * 8);
        *(uint4*)&As[r * ASTR + c8 * 8] = v;
    }
    for (int i = tid; i < 128 * 128; i += 256) {
        int k = i >> 7, n = i & 127;
        Bs[n * ASTR + k] = (unsigned short)bf16rne(W[i]);
    }
    __syncthreads();

    int wv = tid >> 6, lane = tid & 63;
    int m = lane & 15, quad = lane >> 4;
    const unsigned short* arow = &As[(16 * wv + m) * ASTR + quad * 8];
    f32x4 acc[8];
#pragma unroll
    for (int t = 0; t < 8; t++) {
        const unsigned short* brow = &Bs[(t * 16 + m) * ASTR + quad * 8];
        f32x4 c = {0.f, 0.f, 0.f, 0.f};
#pragma unroll
        for (int s = 0; s < 4; s++) {
            short8 a = *(const short8*)(arow + s * 32);
            short8 b = *(const short8*)(brow + s * 32);
            c = __builtin_amdgcn_mfma_f32_16x16x32_bf16(a, b, c, 0, 0, 0);
        }
        acc[t] = c;
    }
#pragma unroll
    for (int t = 0; t < 8; t++) {
        float bv = bias[t * 16 + m];
#pragma unroll
        for (int r = 0; r < 4; r++) {
            int grow = row0 + 16 * wv + quad * 4 + r;
            if (grow >= N) continue;
            float v = acc[t][r] + bv;
            size_t oidx = (size_t)grow * DD + t * 16 + m;
            if (mode == 0) {
                v = 0.5f * v * (1.0f + erff(v * 0.70710678118654752f));
                ((unsigned short*)outp)[oidx] = (unsigned short)bf16rne(v);
            } else {
                ((float*)outp)[oidx] = v;
            }
        }
    }
}

extern "C" void kernel_launch(void* const* d_in, const int* in_sizes, int n_in,
                              void* d_out, int out_size, void* d_ws, size_t ws_size,
                              hipStream_t stream) {
    const float* feat = (const float*)d_in[0];
    const int*   e_feat = (const int*)d_in[1];
    const int*   src = (const int*)d_in[2];
    const int*   dst = (const int*)d_in[3];
    const float* emb = (const float*)d_in[4];
    const float* We1 = (const float*)d_in[5];
    const float* be1 = (const float*)d_in[6];
    const float* We2 = (const float*)d_in[7];
    const float* be2 = (const float*)d_in[8];
    const float* W1  = (const float*)d_in[9];
    const float* b1  = (const float*)d_in[10];
    const float* W2  = (const float*)d_in[11];
    const float* b2  = (const float*)d_in[12];
    float* out = (float*)d_out;

    const int N = NNODES, E = NEDGES;
    const int NBLK = (N + 255) / 256;
    char* ws = (char*)d_ws;
    size_t off = 0;
    uint2* ga  = (uint2*)(ws + off);  off += (size_t)N * 256;     // 12.8 MB bf16 state
    uint2* gb  = (uint2*)(ws + off);  off += (size_t)N * 256;     // 12.8 MB bf16 state
    uint2* f0p = (uint2*)(ws + off);  off += (size_t)N * 256;     // 12.8 MB bf16 feat panels
    int* epay  = (int*)(ws + off);    off += (size_t)E * 4;       // 6.4 MB
    int* rank  = (int*)(ws + off);    off += (size_t)E * 4;       // 6.4 MB
    int* row_ptr = (int*)(ws + off);  off += (size_t)(N + 1) * 4;
    int* excl  = (int*)(ws + off);    off += (size_t)N * 4;
    int* bsum  = (int*)(ws + off);    off += 256 * 4;
    int* cnts  = (int*)(ws + off);    off += (size_t)2 * N * 4;   // incnt|outcnt
    float* gate = (float*)(ws + off); off += 64;
    int* incnt  = cnts;
    int* outcnt = cnts + N;

    hipMemsetAsync(cnts, 0, (size_t)2 * N * 4, stream);
    gate_kernel<<<1, 64, 0, stream>>>(emb, We1, be1, We2, be2, gate);
    deg_in_kernel<<<E / 256, 256, 0, stream>>>(dst, incnt, rank, E);
    scan1_kernel<<<NBLK, 256, 0, stream>>>(incnt, excl, bsum, N);
    scan2_kernel<<<1, 256, 0, stream>>>(bsum, NBLK);
    scan3_kernel<<<(N + 256) / 256 + 1, 256, 0, stream>>>(excl, bsum, row_ptr, N, E);
    scatter_kernel<<<E / 256, 256, 0, stream>>>(src, dst, e_feat, rank, row_ptr,
                                                outcnt, epay, E);
    pscale_kernel<<<(N * 32 + 255) / 256, 256, 0, stream>>>(feat, outcnt, ga, f0p, N);

    const uint2* gin = ga;
    uint2* gout = gb;
    int hblocks = ((N + 3) / 4) * 4;     // 4 nodes/block x 4 panels
    for (int k = 0; k < KHOPS; k++) {
        int last = (k == KHOPS - 1);
        hop_kernel<<<hblocks, 256, 0, stream>>>(gin, f0p, incnt, outcnt, gate,
                                                row_ptr, epay, gout, N, last);
        gin = gout;
        gout = (gout == ga) ? gb : ga;
    }
    // hop9 wrote ga (row-major bf16 final h); gb free -> hidden.
    const unsigned short* hfin = (const unsigned short*)gin;
    unsigned short* hidden = (unsigned short*)gout;
    mlp_mfma_kernel<<<(N + 63) / 64, 256, 0, stream>>>(hfin, W1, b1, hidden, N, 0);
    mlp_mfma_kernel<<<(N + 63) / 64, 256, 0, stream>>>(hidden, W2, b2, out, N, 1);
}

// Round 9
// 1099.907 us; speedup vs baseline: 1.1931x; 1.1931x over previous
//
#include <hip/hip_runtime.h>
#include <hip/hip_fp16.h>
#include <cmath>

// PropConv: K=10 hop gated propagation on a fixed graph + output MLP.
// R9: keep R8's XCD-pinned column panels (FETCH 180->43MB proven) but fix the
// inner loop: (1) sentinel-padded payloads -> no validity/exec logic;
// (2) gate coefficient packed as f16 bits INTO the payload (cvt_f32_f16
// replaces the per-edge dependent LDS gate lookup); (3) batched shfls +
// 4 independent gathers per group (R5's ILP shape).

#define NNODES 50000
#define NEDGES 1600000
#define DD 128
#define KHOPS 10
#define ALPHA 0.1f
#define NPAN 4

typedef short short8 __attribute__((ext_vector_type(8)));
typedef float f32x4 __attribute__((ext_vector_type(4)));

static __device__ __forceinline__ unsigned bf16rne(float x) {
    unsigned u = __float_as_uint(x);
    return (u + 0x7FFFu + ((u >> 16) & 1u)) >> 16;
}
static __device__ __forceinline__ float bf_lo(unsigned w) { return __uint_as_float(w << 16); }
static __device__ __forceinline__ float bf_hi(unsigned w) { return __uint_as_float(w & 0xFFFF0000u); }

// 8-entry gate table: gate MLP has only 8 distinct inputs (etypes).
__global__ void gate_kernel(const float* __restrict__ emb, const float* __restrict__ We1,
                            const float* __restrict__ be1, const float* __restrict__ We2,
                            const float* __restrict__ be2, float* __restrict__ gate) {
    int t = threadIdx.x;
    if (t >= 8) return;
    float acc2 = 0.0f;
    for (int j = 0; j < 32; j++) {
        float a = be1[j];
        for (int k = 0; k < DD; k++) a += emb[t * DD + k] * We1[k * 32 + j];
        float g = 0.5f * a * (1.0f + erff(a * 0.70710678118654752f));  // exact GELU
        acc2 += g * We2[j];
    }
    acc2 += be2[0];
    gate[t] = 1.0f + 1.0f / (1.0f + expf(-acc2));   // 1 + sigmoid
}

// In-degree histogram; returned old count = edge's rank within its dst segment.
__global__ void deg_in_kernel(const int* __restrict__ dst, int* __restrict__ incnt,
                              int* __restrict__ rank, int E) {
    int e = blockIdx.x * blockDim.x + threadIdx.x;
    if (e < E) rank[e] = atomicAdd(&incnt[dst[e]], 1);
}

// ---- 3-kernel multi-block exclusive scan of incnt -> row_ptr ----
__global__ __launch_bounds__(256) void scan1_kernel(const int* __restrict__ cnt,
                                                    int* __restrict__ excl,
                                                    int* __restrict__ bsum, int N) {
    __shared__ int sh[256];
    int t = threadIdx.x;
    int g = blockIdx.x * 256 + t;
    int v = (g < N) ? cnt[g] : 0;
    sh[t] = v;
    __syncthreads();
    for (int off = 1; off < 256; off <<= 1) {
        int u = 0;
        if (t >= off) u = sh[t - off];
        __syncthreads();
        sh[t] += u;
        __syncthreads();
    }
    if (g < N) excl[g] = sh[t] - v;
    if (t == 255) bsum[blockIdx.x] = sh[255];
}
__global__ __launch_bounds__(256) void scan2_kernel(int* __restrict__ bsum, int nb) {
    __shared__ int sh[256];
    int t = threadIdx.x;
    int v = (t < nb) ? bsum[t] : 0;
    sh[t] = v;
    __syncthreads();
    for (int off = 1; off < 256; off <<= 1) {
        int u = 0;
        if (t >= off) u = sh[t - off];
        __syncthreads();
        sh[t] += u;
        __syncthreads();
    }
    if (t < nb) bsum[t] = sh[t] - v;
}
__global__ __launch_bounds__(256) void scan3_kernel(const int* __restrict__ excl,
                                                    const int* __restrict__ bsum,
                                                    int* __restrict__ row_ptr, int N, int E) {
    int g = blockIdx.x * 256 + threadIdx.x;
    if (g < N) row_ptr[g] = excl[g] + bsum[g >> 8];
    if (g == N) row_ptr[N] = E;
}

// Place edges: pos = row_ptr[dst] + rank (no cursor atomic). Payload packs the
// gate coefficient as f16 bits: epay = f16(gate[et])<<16 | src. Builds outcnt.
__global__ void scatter_kernel(const int* __restrict__ src, const int* __restrict__ dst,
                               const int* __restrict__ ef, const int* __restrict__ rank,
                               const int* __restrict__ row_ptr, const float* __restrict__ gate,
                               int* __restrict__ outcnt, unsigned* __restrict__ epay, int E) {
    int e = blockIdx.x * blockDim.x + threadIdx.x;
    if (e >= E) return;
    int s = src[e];
    int pos = row_ptr[dst[e]] + rank[e];
    unsigned cb = (unsigned)__half_as_ushort(__float2half(gate[ef[e]]));
    epay[pos] = (cb << 16) | (unsigned)s;
    atomicAdd(&outcnt[s], 1);
}

// Panel-major bf16: g0[p][n][sub] = bf16(feat*srcn), f0p[p][n][sub] = bf16(feat).
__global__ void pscale_kernel(const float* __restrict__ feat, const int* __restrict__ outcnt,
                              uint2* __restrict__ g0, uint2* __restrict__ f0p, int N) {
    int i = blockIdx.x * blockDim.x + threadIdx.x;   // uint2 units, panel-major
    if (i >= N * 32) return;
    int pan = i / (N * 8);
    int rem = i - pan * (N * 8);
    int node = rem >> 3;
    int sub = rem & 7;
    int oc = outcnt[node]; if (oc < 1) oc = 1;
    float sn = rsqrtf((float)oc);
    float4 v = ((const float4*)feat)[node * 32 + pan * 8 + sub];
    uint2 f, g;
    f.x = bf16rne(v.x) | (bf16rne(v.y) << 16);
    f.y = bf16rne(v.z) | (bf16rne(v.w) << 16);
    g.x = bf16rne(v.x * sn) | (bf16rne(v.y * sn) << 16);
    g.y = bf16rne(v.z * sn) | (bf16rne(v.w * sn) << 16);
    f0p[i] = f;
    g0[i] = g;
}

// Wave = 1 dst node x 1 panel (panel = blk&3 -> XCD-pinned; 3.2MB panel
// resident in 2 XCDs' L2). 8 segments x 8 lanes; lane = uint2 (4 bf16 cols).
// Chunk of <=64 payloads loaded coalesced with SENTINEL padding (coef=0,
// src=0) -> unconditional inner loop. Per group: 4 batched shfls, 4
// independent 64B gathers, 4 cvt_f32_f16, 16 FMA. No LDS in the loop.
__global__ __launch_bounds__(256) void hop_kernel(const uint2* __restrict__ g_in,
                                                  const uint2* __restrict__ f0p,
                                                  const int* __restrict__ incnt,
                                                  const int* __restrict__ outcnt,
                                                  const int* __restrict__ row_ptr,
                                                  const unsigned* __restrict__ epay,
                                                  uint2* __restrict__ g_out,
                                                  int N, int last) {
    int pan = blockIdx.x & 3;
    int node = (blockIdx.x >> 2) * 4 + (threadIdx.x >> 6);
    if (node >= N) return;
    int lane = threadIdx.x & 63;
    int seg = lane >> 3, sub = lane & 7;
    const uint2* gp = g_in + (size_t)pan * N * 8;
    int beg = row_ptr[node], end = row_ptr[node + 1];
    float a0 = 0.f, a1 = 0.f, a2 = 0.f, a3 = 0.f;
    for (int base = beg; base < end; base += 64) {
        int n = end - base; if (n > 64) n = 64;
        unsigned p = 0u;                         // sentinel: coef=0, src=0
        if (lane < n) p = epay[base + lane];
        int groups = (n + 31) >> 5;              // wave-uniform
        for (int g = 0; g < groups; g++) {
            int j0 = (g << 5) + seg;
            unsigned pe0 = (unsigned)__shfl((int)p, j0, 64);
            unsigned pe1 = (unsigned)__shfl((int)p, j0 + 8, 64);
            unsigned pe2 = (unsigned)__shfl((int)p, j0 + 16, 64);
            unsigned pe3 = (unsigned)__shfl((int)p, j0 + 24, 64);
            uint2 v0 = gp[(pe0 & 0xFFFFu) * 8 + sub];
            uint2 v1 = gp[(pe1 & 0xFFFFu) * 8 + sub];
            uint2 v2 = gp[(pe2 & 0xFFFFu) * 8 + sub];
            uint2 v3 = gp[(pe3 & 0xFFFFu) * 8 + sub];
            float c0 = __half2float(__ushort_as_half((unsigned short)(pe0 >> 16)));
            float c1 = __half2float(__ushort_as_half((unsigned short)(pe1 >> 16)));
            float c2 = __half2float(__ushort_as_half((unsigned short)(pe2 >> 16)));
            float c3 = __half2float(__ushort_as_half((unsigned short)(pe3 >> 16)));
            a0 += c0 * bf_lo(v0.x); a1 += c0 * bf_hi(v0.x);
            a2 += c0 * bf_lo(v0.y); a3 += c0 * bf_hi(v0.y);
            a0 += c1 * bf_lo(v1.x); a1 += c1 * bf_hi(v1.x);
            a2 += c1 * bf_lo(v1.y); a3 += c1 * bf_hi(v1.y);
            a0 += c2 * bf_lo(v2.x); a1 += c2 * bf_hi(v2.x);
            a2 += c2 * bf_lo(v2.y); a3 += c2 * bf_hi(v2.y);
            a0 += c3 * bf_lo(v3.x); a1 += c3 * bf_hi(v3.x);
            a2 += c3 * bf_lo(v3.y); a3 += c3 * bf_hi(v3.y);
        }
    }
#pragma unroll
    for (int d = 8; d < 64; d <<= 1) {
        a0 += __shfl_xor(a0, d, 64);
        a1 += __shfl_xor(a1, d, 64);
        a2 += __shfl_xor(a2, d, 64);
        a3 += __shfl_xor(a3, d, 64);
    }
    if (lane < 8) {                              // sub = lane
        int ic = incnt[node]; if (ic < 1) ic = 1;
        float dn = rsqrtf((float)ic) * (1.0f - ALPHA);
        uint2 fv = f0p[(size_t)pan * N * 8 + (size_t)node * 8 + lane];
        float h0 = dn * a0 + ALPHA * bf_lo(fv.x);
        float h1 = dn * a1 + ALPHA * bf_hi(fv.x);
        float h2 = dn * a2 + ALPHA * bf_lo(fv.y);
        float h3 = dn * a3 + ALPHA * bf_hi(fv.y);
        float sc = 1.0f;
        if (!last) { int oc = outcnt[node]; if (oc < 1) oc = 1; sc = rsqrtf((float)oc); }
        uint2 o;
        o.x = bf16rne(h0 * sc) | (bf16rne(h1 * sc) << 16);
        o.y = bf16rne(h2 * sc) | (bf16rne(h3 * sc) << 16);
        size_t oidx = last ? ((size_t)node * 32 + pan * 8 + lane)            // row-major for MLP
                           : ((size_t)pan * N * 8 + (size_t)node * 8 + lane); // panel-major
        g_out[oidx] = o;
    }
}

// bf16 MFMA MLP layer (verified gfx950 16x16x32 layouts).
#define ASTR 136
__global__ __launch_bounds__(256) void mlp_mfma_kernel(const unsigned short* __restrict__ in,
                                                       const float* __restrict__ W,
                                                       const float* __restrict__ bias,
                                                       void* __restrict__ outp,
                                                       int N, int mode) {  // mode0: gelu+bf16; mode1: f32
    __shared__ unsigned short As[64 * ASTR];
    __shared__ unsigned short Bs[128 * ASTR];
    int tid = threadIdx.x;
    int row0 = blockIdx.x * 64;
    for (int i = tid; i < 64 * 16; i += 256) {
        int r = i >> 4, c8 = i & 15;
        int gr = row0 + r; if (gr >= N) gr = N - 1;
        uint4 v = *(const uint4*)(in + (size_t)gr * DD + c8 * 8);
        *(uint4*)&As[r * ASTR + c8 * 8] = v;
    }
    for (int i = tid; i < 128 * 128; i += 256) {
        int k = i >> 7, n = i & 127;
        Bs[n * ASTR + k] = (unsigned short)bf16rne(W[i]);
    }
    __syncthreads();

    int wv = tid >> 6, lane = tid & 63;
    int m = lane & 15, quad = lane >> 4;
    const unsigned short* arow = &As[(16 * wv + m) * ASTR + quad * 8];
    f32x4 acc[8];
#pragma unroll
    for (int t = 0; t < 8; t++) {
        const unsigned short* brow = &Bs[(t * 16 + m) * ASTR + quad * 8];
        f32x4 c = {0.f, 0.f, 0.f, 0.f};
#pragma unroll
        for (int s = 0; s < 4; s++) {
            short8 a = *(const short8*)(arow + s * 32);
            short8 b = *(const short8*)(brow + s * 32);
            c = __builtin_amdgcn_mfma_f32_16x16x32_bf16(a, b, c, 0, 0, 0);
        }
        acc[t] = c;
    }
#pragma unroll
    for (int t = 0; t < 8; t++) {
        float bv = bias[t * 16 + m];
#pragma unroll
        for (int r = 0; r < 4; r++) {
            int grow = row0 + 16 * wv + quad * 4 + r;
            if (grow >= N) continue;
            float v = acc[t][r] + bv;
            size_t oidx = (size_t)grow * DD + t * 16 + m;
            if (mode == 0) {
                v = 0.5f * v * (1.0f + erff(v * 0.70710678118654752f));
                ((unsigned short*)outp)[oidx] = (unsigned short)bf16rne(v);
            } else {
                ((float*)outp)[oidx] = v;
            }
        }
    }
}

extern "C" void kernel_launch(void* const* d_in, const int* in_sizes, int n_in,
                              void* d_out, int out_size, void* d_ws, size_t ws_size,
                              hipStream_t stream) {
    const float* feat = (const float*)d_in[0];
    const int*   e_feat = (const int*)d_in[1];
    const int*   src = (const int*)d_in[2];
    const int*   dst = (const int*)d_in[3];
    const float* emb = (const float*)d_in[4];
    const float* We1 = (const float*)d_in[5];
    const float* be1 = (const float*)d_in[6];
    const float* We2 = (const float*)d_in[7];
    const float* be2 = (const float*)d_in[8];
    const float* W1  = (const float*)d_in[9];
    const float* b1  = (const float*)d_in[10];
    const float* W2  = (const float*)d_in[11];
    const float* b2  = (const float*)d_in[12];
    float* out = (float*)d_out;

    const int N = NNODES, E = NEDGES;
    const int NBLK = (N + 255) / 256;
    char* ws = (char*)d_ws;
    size_t off = 0;
    uint2* ga  = (uint2*)(ws + off);  off += (size_t)N * 256;     // 12.8 MB bf16 state
    uint2* gb  = (uint2*)(ws + off);  off += (size_t)N * 256;     // 12.8 MB bf16 state
    uint2* f0p = (uint2*)(ws + off);  off += (size_t)N * 256;     // 12.8 MB bf16 feat panels
    unsigned* epay = (unsigned*)(ws + off); off += (size_t)E * 4; // 6.4 MB
    int* rank  = (int*)(ws + off);    off += (size_t)E * 4;       // 6.4 MB
    int* row_ptr = (int*)(ws + off);  off += (size_t)(N + 1) * 4;
    int* excl  = (int*)(ws + off);    off += (size_t)N * 4;
    int* bsum  = (int*)(ws + off);    off += 256 * 4;
    int* cnts  = (int*)(ws + off);    off += (size_t)2 * N * 4;   // incnt|outcnt
    float* gate = (float*)(ws + off); off += 64;
    int* incnt  = cnts;
    int* outcnt = cnts + N;

    hipMemsetAsync(cnts, 0, (size_t)2 * N * 4, stream);
    gate_kernel<<<1, 64, 0, stream>>>(emb, We1, be1, We2, be2, gate);
    deg_in_kernel<<<E / 256, 256, 0, stream>>>(dst, incnt, rank, E);
    scan1_kernel<<<NBLK, 256, 0, stream>>>(incnt, excl, bsum, N);
    scan2_kernel<<<1, 256, 0, stream>>>(bsum, NBLK);
    scan3_kernel<<<(N + 256) / 256 + 1, 256, 0, stream>>>(excl, bsum, row_ptr, N, E);
    scatter_kernel<<<E / 256, 256, 0, stream>>>(src, dst, e_feat, rank, row_ptr,
                                                gate, outcnt, epay, E);
    pscale_kernel<<<(N * 32 + 255) / 256, 256, 0, stream>>>(feat, outcnt, ga, f0p, N);

    const uint2* gin = ga;
    uint2* gout = gb;
    int hblocks = ((N + 3) / 4) * 4;     // 4 nodes/block x 4 panels
    for (int k = 0; k < KHOPS; k++) {
        int last = (k == KHOPS - 1);
        hop_kernel<<<hblocks, 256, 0, stream>>>(gin, f0p, incnt, outcnt,
                                                row_ptr, epay, gout, N, last);
        gin = gout;
        gout = (gout == ga) ? gb : ga;
    }
    // hop9 wrote row-major bf16 final h into gin's buffer; gout free -> hidden.
    const unsigned short* hfin = (const unsigned short*)gin;
    unsigned short* hidden = (unsigned short*)gout;
    mlp_mfma_kernel<<<(N + 63) / 64, 256, 0, stream>>>(hfin, W1, b1, hidden, N, 0);
    mlp_mfma_kernel<<<(N + 63) / 64, 256, 0, stream>>>(hidden, W2, b2, out, N, 1);
}